// Round 22
// baseline (80.813 us; speedup 1.0000x reference)
//
#include <hip/hip_runtime.h>
#include <hip/hip_bf16.h>

#define B_ 8
#define N_ 2048
#define D_ 512
#define DK_ 64

typedef float f32x4 __attribute__((ext_vector_type(4)));
typedef short bf16x8 __attribute__((ext_vector_type(8)));
typedef unsigned short u16;

__device__ __forceinline__ u16 f2bf(float f) {
  union { float f; unsigned u; } v; v.f = f;
  unsigned r = v.u + 0x7FFFu + ((v.u >> 16) & 1u);  // RNE, inputs finite
  return (u16)(r >> 16);
}

#define MFMA32(a, b, cacc) __builtin_amdgcn_mfma_f32_16x16x32_bf16((a), (b), (cacc), 0, 0, 0)

// lgkm-only barrier (validated R4/R10/R17/R18/R19/R21 incl. graph-replay)
#define BARRIER_LGKM() do {                                   \
    asm volatile("s_waitcnt lgkmcnt(0)" ::: "memory");        \
    __builtin_amdgcn_s_barrier();                             \
    asm volatile("" ::: "memory");                            \
  } while (0)

// ===========================================================================
// Fragment layouts (every attn global load = 64 lanes x 16B contiguous 1KB):
//  Qf/Kf: elem((b*128 + slab)*2 + ks)*512 + lane*8 + i
//         holds  M[slab*16 + (lane&15)][ks*32 + (lane>>4)*8 + i]
//  Vf:    elem(((b*32 + dt)*32 + nt)*2 + ks)*512 + lane*8 + i
//         holds  X[nt*64 + ks*32 + (lane>>4)*8 + i][dt*16 + (lane&15)]
//         (window-linear: elem ((b*32+dt)*64 + j)*512 for 32-kv window j)
// ===========================================================================

// ---------------------------------------------------------------------------
// prep (validated R18/R19/R21, byte-identical): fused vt+proj, one X pass.
// ---------------------------------------------------------------------------
__global__ __launch_bounds__(256) void prep_kernel(
    const float* __restrict__ h, const float* __restrict__ X,
    const float* __restrict__ WQ, const float* __restrict__ bQ,
    const float* __restrict__ WK, const float* __restrict__ bK,
    u16* __restrict__ Qf, u16* __restrict__ Kf, u16* __restrict__ Vf) {
  int bid = blockIdx.x;
  int b = bid & 7, nt = bid >> 3;
  int n0 = nt * 64;
  int t = threadIdx.x, w = t >> 6, l = t & 63, g = l >> 4, c = l & 15;

  __shared__ u16 Xb16[64][520];

  int arow = n0 + w * 16 + c;
  const float* hrow = h + ((size_t)b * N_ + arow) * D_;
  const float* Xrow = X + ((size_t)b * N_ + arow) * D_;
  f32x4 accq[4], acck[4];
#pragma unroll
  for (int cf = 0; cf < 4; ++cf) {
    accq[cf] = (f32x4){0.f, 0.f, 0.f, 0.f};
    acck[cf] = (f32x4){0.f, 0.f, 0.f, 0.f};
  }
  for (int k0 = 0; k0 < D_; k0 += 32) {
    bf16x8 ah, ax;
    {
      f32x4 h0 = *reinterpret_cast<const f32x4*>(hrow + k0 + 8 * g);
      f32x4 h1 = *reinterpret_cast<const f32x4*>(hrow + k0 + 8 * g + 4);
      f32x4 x0 = *reinterpret_cast<const f32x4*>(Xrow + k0 + 8 * g);
      f32x4 x1 = *reinterpret_cast<const f32x4*>(Xrow + k0 + 8 * g + 4);
#pragma unroll
      for (int i = 0; i < 4; ++i) {
        ah[i] = (short)f2bf(h0[i]); ah[i + 4] = (short)f2bf(h1[i]);
        ax[i] = (short)f2bf(x0[i]); ax[i + 4] = (short)f2bf(x1[i]);
      }
    }
    *reinterpret_cast<bf16x8*>(&Xb16[w * 16 + c][k0 + 8 * g]) = ax;
#pragma unroll
    for (int cf = 0; cf < 4; ++cf) {
      bf16x8 bq, bk;
#pragma unroll
      for (int i = 0; i < 8; ++i) {
        int kk = k0 + 8 * g + i;
        bq[i] = (short)f2bf(WQ[(size_t)kk * DK_ + cf * 16 + c]);
        bk[i] = (short)f2bf(WK[(size_t)kk * DK_ + cf * 16 + c]);
      }
      accq[cf] = MFMA32(ah, bq, accq[cf]);
      acck[cf] = MFMA32(ax, bk, acck[cf]);
    }
  }
#pragma unroll
  for (int cf = 0; cf < 4; ++cf) {
    float vq = bQ[cf * 16 + c], vk = bK[cf * 16 + c];
    int ks = cf >> 1;
    int g2 = ((cf & 1) * 16 + c) >> 3;
    int i2 = c & 7;
#pragma unroll
    for (int r = 0; r < 4; ++r) {
      size_t e = ((size_t)(b * 128 + nt * 4 + w) * 2 + ks) * 512 +
                 (g2 * 16 + 4 * g + r) * 8 + i2;
      Qf[e] = f2bf((accq[cf][r] + vq) * 0.125f);
      Kf[e] = f2bf(acck[cf][r] + vk);
    }
  }

  __syncthreads();

#pragma unroll
  for (int dtl = 0; dtl < 8; ++dtl) {
    int dt = w * 8 + dtl;
#pragma unroll
    for (int ks = 0; ks < 2; ++ks) {
      bf16x8 v;
#pragma unroll
      for (int i = 0; i < 8; ++i) v[i] = Xb16[ks * 32 + 8 * g + i][dt * 16 + c];
      *reinterpret_cast<bf16x8*>(
          Vf + (((size_t)(b * 32 + dt) * 32 + nt) * 2 + ks) * 512 + l * 8) = v;
    }
  }
}

// ---------------------------------------------------------------------------
// attn: 128q x 256d blocks (grid 256 = b*8 x dh*2 x qt*16, 1/CU, 8 waves).
// Halves V traffic per CU-window (each V line serves 128 q): L2->L1 refill
// 36KB -> 20KB/window -- the R6-R21-diagnosed bandwidth floor. S computed
// once per dh (2x total, cheap). Wave w: S for slabs qhA=w>>1, qhB=4+(w>>1)
// (kq=w&1 half); PV d-slice = w*32 (2 V-frags), o[8][2]. Sync = R21's
// validated pair rotation (P 4-buf, barrier every 2 windows, K pair-top,
// V in-place reload post-PV).
// ---------------------------------------------------------------------------
__global__ __launch_bounds__(512, 1) void attn_kernel(
    const u16* __restrict__ Qf, const u16* __restrict__ Kf,
    const u16* __restrict__ Vf, float* __restrict__ out) {
  int bid = blockIdx.x;
  int b = bid & 7, dh = (bid >> 3) & 1, qt = bid >> 4;
  int q0 = qt * 128;
  int t = threadIdx.x, w = t >> 6, l = t & 63, g = l >> 4, c = l & 15;
  int kq = w & 1, qhA = w >> 1, qhB = 4 + (w >> 1);

  __shared__ u16 Plds[4][128][40];  // P 4-buffer [q 128][kv 32], stride 40
  __shared__ float Lp[2][128];

  // Q A-frags: slabs qt*8 + qhA, qt*8 + qhB
  bf16x8 aqA[2], aqB[2];
#pragma unroll
  for (int ks = 0; ks < 2; ++ks) {
    aqA[ks] = *reinterpret_cast<const bf16x8*>(
        Qf + ((size_t)(b * 128 + qt * 8 + qhA) * 2 + ks) * 512 + l * 8);
    aqB[ks] = *reinterpret_cast<const bf16x8*>(
        Qf + ((size_t)(b * 128 + qt * 8 + qhB) * 2 + ks) * 512 + l * 8);
  }

  f32x4 o[8][2];
#pragma unroll
  for (int a = 0; a < 8; ++a)
#pragma unroll
    for (int f = 0; f < 2; ++f) o[a][f] = (f32x4){0.f, 0.f, 0.f, 0.f};
  float lpA[4] = {0.f, 0.f, 0.f, 0.f}, lpB[4] = {0.f, 0.f, 0.f, 0.f};

  // K frag (window j, ks): Kbase + (4*j + ks)*512  (kq half folded in base)
  const u16* Kbase = Kf + ((size_t)(b * 256 + 2 * kq)) * 512 + l * 8;
  // V frag (f, window j): Vbase + (f*64 + j)*512   (dt = dh*16 + w*2 + f)
  const u16* Vbase = Vf + ((size_t)(b * 32 + dh * 16 + w * 2) * 64) * 512 + l * 8;

  bf16x8 kb0[2], kb1[2], vb0[2], vb1[2];

  // S+exp+P-write for window jw from kb (both slabs)
  auto sexp = [&](bf16x8 (&kb)[2], int pb) {
    {
      f32x4 s = (f32x4){0.f, 0.f, 0.f, 0.f};
      s = MFMA32(aqA[0], kb[0], s); s = MFMA32(aqA[1], kb[1], s);
#pragma unroll
      for (int r = 0; r < 4; ++r) {
        float p = __expf(s[r]); lpA[r] += p;
        Plds[pb][qhA * 16 + 4 * g + r][kq * 16 + c] = f2bf(p);
      }
    }
    {
      f32x4 s = (f32x4){0.f, 0.f, 0.f, 0.f};
      s = MFMA32(aqB[0], kb[0], s); s = MFMA32(aqB[1], kb[1], s);
#pragma unroll
      for (int r = 0; r < 4; ++r) {
        float p = __expf(s[r]); lpB[r] += p;
        Plds[pb][qhB * 16 + 4 * g + r][kq * 16 + c] = f2bf(p);
      }
    }
  };
  // PV for buffer pb against V regs vb
  auto pv = [&](int pb, bf16x8 (&vb)[2]) {
    __builtin_amdgcn_s_setprio(1);
#pragma unroll
    for (int a = 0; a < 8; ++a) {
      bf16x8 pa = *reinterpret_cast<const bf16x8*>(&Plds[pb][a * 16 + c][8 * g]);
      o[a][0] = MFMA32(pa, vb[0], o[a][0]);
      o[a][1] = MFMA32(pa, vb[1], o[a][1]);
    }
    __builtin_amdgcn_s_setprio(0);
  };

  // ---- prologue: K(0),K(1); V(0),V(1); S(0)->P0, S(1)->P1; barrier
#pragma unroll
  for (int ks = 0; ks < 2; ++ks) {
    kb0[ks] = *reinterpret_cast<const bf16x8*>(Kbase + (size_t)ks * 512);
    kb1[ks] = *reinterpret_cast<const bf16x8*>(Kbase + (size_t)(4 + ks) * 512);
  }
#pragma unroll
  for (int f = 0; f < 2; ++f) {
    vb0[f] = *reinterpret_cast<const bf16x8*>(Vbase + (size_t)(f * 64 + 0) * 512);
    vb1[f] = *reinterpret_cast<const bf16x8*>(Vbase + (size_t)(f * 64 + 1) * 512);
  }
  sexp(kb0, 0);
  sexp(kb1, 1);
  BARRIER_LGKM();

  // pair(k2): load K(k2+2)->kb0,K(k2+3)->kb1; PV(k2) from Plds[pR0]+vb0,
  // reload vb0<-V(k2+2); PV(k2+1) from Plds[pR1]+vb1, reload vb1<-V(k2+3);
  // S(k2+2)->P[pW0], S(k2+3)->P[pW1]; barrier.  (R21-validated rotation.)
  auto pair = [&](int k2, int pR0, int pR1, int pW0, int pW1) {
#pragma unroll
    for (int ks = 0; ks < 2; ++ks) {
      kb0[ks] = *reinterpret_cast<const bf16x8*>(
          Kbase + (size_t)(4 * (k2 + 2) + ks) * 512);
      kb1[ks] = *reinterpret_cast<const bf16x8*>(
          Kbase + (size_t)(4 * (k2 + 3) + ks) * 512);
    }

    pv(pR0, vb0);
#pragma unroll
    for (int f = 0; f < 2; ++f)
      vb0[f] = *reinterpret_cast<const bf16x8*>(
          Vbase + (size_t)(f * 64 + k2 + 2) * 512);

    pv(pR1, vb1);
#pragma unroll
    for (int f = 0; f < 2; ++f)
      vb1[f] = *reinterpret_cast<const bf16x8*>(
          Vbase + (size_t)(f * 64 + k2 + 3) * 512);

    sexp(kb0, pW0);
    sexp(kb1, pW1);

    BARRIER_LGKM();
  };

#pragma unroll 1
  for (int k2 = 0; k2 < 60; k2 += 4) {
    pair(k2, 0, 1, 2, 3);
    pair(k2 + 2, 2, 3, 0, 1);
  }
  pair(60, 0, 1, 2, 3);

  // ---- epilogue: PV(62) from Plds[2]+vb0(=V62); PV(63) from Plds[3]+vb1
  pv(2, vb0);
  pv(3, vb1);

  // ---- denominator: reduce over 16 c-lanes; write both slabs; combine kq
#pragma unroll
  for (int r = 0; r < 4; ++r) {
    float vA = lpA[r], vB = lpB[r];
    vA += __shfl_xor(vA, 1); vA += __shfl_xor(vA, 2);
    vA += __shfl_xor(vA, 4); vA += __shfl_xor(vA, 8);
    vB += __shfl_xor(vB, 1); vB += __shfl_xor(vB, 2);
    vB += __shfl_xor(vB, 4); vB += __shfl_xor(vB, 8);
    lpA[r] = vA; lpB[r] = vB;
  }
  if (c == 0) {
#pragma unroll
    for (int r = 0; r < 4; ++r) {
      Lp[kq][qhA * 16 + 4 * g + r] = lpA[r];
      Lp[kq][qhB * 16 + 4 * g + r] = lpB[r];
    }
  }
  __syncthreads();

  float* outb = out + ((size_t)b * N_ + q0) * D_ + dh * 256;
#pragma unroll
  for (int a = 0; a < 8; ++a)
#pragma unroll
    for (int r = 0; r < 4; ++r) {
      int ql = a * 16 + 4 * g + r;
      float L = Lp[0][ql] + Lp[1][ql];
      float inv = 1.0f / L;
#pragma unroll
      for (int f = 0; f < 2; ++f)
        outb[(size_t)ql * D_ + w * 32 + f * 16 + c] = o[a][f][r] * inv;
    }
}

// ---------------------------------------------------------------------------
extern "C" void kernel_launch(void* const* d_in, const int* in_sizes, int n_in,
                              void* d_out, int out_size, void* d_ws, size_t ws_size,
                              hipStream_t stream) {
  const float* X  = (const float*)d_in[0];
  const float* h  = (const float*)d_in[1];
  const float* WQ = (const float*)d_in[2];
  const float* bQ = (const float*)d_in[3];
  const float* WK = (const float*)d_in[4];
  const float* bK = (const float*)d_in[5];
  float* out = (float*)d_out;

  u16* Vf = (u16*)d_ws;                                // 16 MB
  u16* Qf = Vf + (size_t)B_ * D_ * N_;                 // 2 MB
  u16* Kf = Qf + (size_t)B_ * N_ * DK_;                // 2 MB

  prep_kernel<<<dim3(256), dim3(256), 0, stream>>>(h, X, WQ, bQ, WK, bK, Qf, Kf, Vf);
  attn_kernel<<<dim3(256), dim3(512), 0, stream>>>(Qf, Kf, Vf, out);
}

// Round 23
// 73.288 us; speedup vs baseline: 1.1027x; 1.1027x over previous
//
#include <hip/hip_runtime.h>
#include <hip/hip_bf16.h>

#define B_ 8
#define N_ 2048
#define D_ 512
#define DK_ 64

typedef float f32x4 __attribute__((ext_vector_type(4)));
typedef short bf16x8 __attribute__((ext_vector_type(8)));
typedef unsigned short u16;

__device__ __forceinline__ u16 f2bf(float f) {
  union { float f; unsigned u; } v; v.f = f;
  unsigned r = v.u + 0x7FFFu + ((v.u >> 16) & 1u);  // RNE, inputs finite
  return (u16)(r >> 16);
}

#define MFMA32(a, b, cacc) __builtin_amdgcn_mfma_f32_16x16x32_bf16((a), (b), (cacc), 0, 0, 0)

// lgkm-only barrier (validated R4/R10/R17/R18/R19 incl. graph-replay reval)
#define BARRIER_LGKM() do {                                   \
    asm volatile("s_waitcnt lgkmcnt(0)" ::: "memory");        \
    __builtin_amdgcn_s_barrier();                             \
    asm volatile("" ::: "memory");                            \
  } while (0)

// ===========================================================================
// Fragment layouts (every attn global load = 64 lanes x 16B contiguous 1KB):
//  Qf/Kf: elem((b*128 + slab)*2 + ks)*512 + lane*8 + i
//         holds  M[slab*16 + (lane&15)][ks*32 + (lane>>4)*8 + i]
//  Vf:    elem(((b*32 + dt)*32 + nt)*2 + ks)*512 + lane*8 + i
//         holds  X[nt*64 + ks*32 + (lane>>4)*8 + i][dt*16 + (lane&15)]
//         (window-linear: elem ((b*32+dt)*64 + j)*512 for 32-kv window j)
// ===========================================================================

// ---------------------------------------------------------------------------
// prep (validated R18/R19, byte-identical): fused vt+proj, one pass over X.
// ---------------------------------------------------------------------------
__global__ __launch_bounds__(256) void prep_kernel(
    const float* __restrict__ h, const float* __restrict__ X,
    const float* __restrict__ WQ, const float* __restrict__ bQ,
    const float* __restrict__ WK, const float* __restrict__ bK,
    u16* __restrict__ Qf, u16* __restrict__ Kf, u16* __restrict__ Vf) {
  int bid = blockIdx.x;
  int b = bid & 7, nt = bid >> 3;
  int n0 = nt * 64;
  int t = threadIdx.x, w = t >> 6, l = t & 63, g = l >> 4, c = l & 15;

  __shared__ u16 Xb16[64][520];

  int arow = n0 + w * 16 + c;
  const float* hrow = h + ((size_t)b * N_ + arow) * D_;
  const float* Xrow = X + ((size_t)b * N_ + arow) * D_;
  f32x4 accq[4], acck[4];
#pragma unroll
  for (int cf = 0; cf < 4; ++cf) {
    accq[cf] = (f32x4){0.f, 0.f, 0.f, 0.f};
    acck[cf] = (f32x4){0.f, 0.f, 0.f, 0.f};
  }
  for (int k0 = 0; k0 < D_; k0 += 32) {
    bf16x8 ah, ax;
    {
      f32x4 h0 = *reinterpret_cast<const f32x4*>(hrow + k0 + 8 * g);
      f32x4 h1 = *reinterpret_cast<const f32x4*>(hrow + k0 + 8 * g + 4);
      f32x4 x0 = *reinterpret_cast<const f32x4*>(Xrow + k0 + 8 * g);
      f32x4 x1 = *reinterpret_cast<const f32x4*>(Xrow + k0 + 8 * g + 4);
#pragma unroll
      for (int i = 0; i < 4; ++i) {
        ah[i] = (short)f2bf(h0[i]); ah[i + 4] = (short)f2bf(h1[i]);
        ax[i] = (short)f2bf(x0[i]); ax[i + 4] = (short)f2bf(x1[i]);
      }
    }
    *reinterpret_cast<bf16x8*>(&Xb16[w * 16 + c][k0 + 8 * g]) = ax;
#pragma unroll
    for (int cf = 0; cf < 4; ++cf) {
      bf16x8 bq, bk;
#pragma unroll
      for (int i = 0; i < 8; ++i) {
        int kk = k0 + 8 * g + i;
        bq[i] = (short)f2bf(WQ[(size_t)kk * DK_ + cf * 16 + c]);
        bk[i] = (short)f2bf(WK[(size_t)kk * DK_ + cf * 16 + c]);
      }
      accq[cf] = MFMA32(ah, bq, accq[cf]);
      acck[cf] = MFMA32(ax, bk, acck[cf]);
    }
  }
#pragma unroll
  for (int cf = 0; cf < 4; ++cf) {
    float vq = bQ[cf * 16 + c], vk = bK[cf * 16 + c];
    int ks = cf >> 1;
    int g2 = ((cf & 1) * 16 + c) >> 3;
    int i2 = c & 7;
#pragma unroll
    for (int r = 0; r < 4; ++r) {
      size_t e = ((size_t)(b * 128 + nt * 4 + w) * 2 + ks) * 512 +
                 (g2 * 16 + 4 * g + r) * 8 + i2;
      Qf[e] = f2bf((accq[cf][r] + vq) * 0.125f);
      Kf[e] = f2bf(acck[cf][r] + vk);
    }
  }

  __syncthreads();

#pragma unroll
  for (int dtl = 0; dtl < 8; ++dtl) {
    int dt = w * 8 + dtl;
#pragma unroll
    for (int ks = 0; ks < 2; ++ks) {
      bf16x8 v;
#pragma unroll
      for (int i = 0; i < 8; ++i) v[i] = Xb16[ks * 32 + 8 * g + i][dt * 16 + c];
      *reinterpret_cast<bf16x8*>(
          Vf + (((size_t)(b * 32 + dt) * 32 + nt) * 2 + ks) * 512 + l * 8) = v;
    }
  }
}

// ---------------------------------------------------------------------------
// attn (validated R19, byte-identical; best measured: 46.8 us):
// 256 blocks x 512 threads, 64q x 512d, KVBLK=32; 4-deep P buffering with
// a barrier every TWO windows (33 barriers). Between barriers waves write
// P(2k+2),P(2k+3) and read P(2k),P(2k+1) -- disjoint buffer sets; every
// cross-wave write->read pair separated by >= 1 barrier. K/V 4-slot
// register rotation; lgkm-only barriers keep prefetch in flight.
// ---------------------------------------------------------------------------
__global__ __launch_bounds__(512, 1) void attn_kernel(
    const u16* __restrict__ Qf, const u16* __restrict__ Kf,
    const u16* __restrict__ Vf, float* __restrict__ out) {
  int bid = blockIdx.x;
  int b = bid & 7, qt = bid >> 3;
  int q0 = qt * 64;
  int t = threadIdx.x, w = t >> 6, l = t & 63, g = l >> 4, c = l & 15;
  int qh = w >> 1, kq = w & 1;

  __shared__ u16 Plds[4][64][40];   // P 4-buffer [q 64][kv 32], stride 40 u16
  __shared__ float Lp[2][64];

  bf16x8 aq[2];
#pragma unroll
  for (int ks = 0; ks < 2; ++ks)
    aq[ks] = *reinterpret_cast<const bf16x8*>(
        Qf + ((size_t)(b * 128 + qt * 4 + qh) * 2 + ks) * 512 + l * 8);

  f32x4 o[4][4];
#pragma unroll
  for (int a = 0; a < 4; ++a)
#pragma unroll
    for (int d = 0; d < 4; ++d) o[a][d] = (f32x4){0.f, 0.f, 0.f, 0.f};
  float lp[4] = {0.f, 0.f, 0.f, 0.f};

  const u16* Kbase = Kf + ((size_t)(b * 256 + 2 * kq)) * 512 + l * 8;
  const u16* Vbase = Vf + ((size_t)(b * 32 + w * 4) * 64) * 512 + l * 8;

  bf16x8 kbuf[4][2], vbuf[4][4];

  // ---- prologue: K(0..3)/V(0..3); S(0)->P0, S(1)->P1; barrier
#pragma unroll
  for (int j = 0; j < 4; ++j) {
#pragma unroll
    for (int ks = 0; ks < 2; ++ks)
      kbuf[j][ks] = *reinterpret_cast<const bf16x8*>(
          Kbase + (size_t)(4 * j + ks) * 512);
#pragma unroll
    for (int f = 0; f < 4; ++f)
      vbuf[j][f] = *reinterpret_cast<const bf16x8*>(
          Vbase + (size_t)(f * 64 + j) * 512);
  }
#pragma unroll
  for (int j0 = 0; j0 < 2; ++j0) {
    f32x4 s = (f32x4){0.f, 0.f, 0.f, 0.f};
    s = MFMA32(aq[0], kbuf[j0][0], s);
    s = MFMA32(aq[1], kbuf[j0][1], s);
#pragma unroll
    for (int r = 0; r < 4; ++r) {
      float p = __expf(s[r]); lp[r] += p;
      Plds[j0][qh * 16 + 4 * g + r][kq * 16 + c] = f2bf(p);
    }
  }
  BARRIER_LGKM();

  // pair body: windows (k2, k2+1). S(k2+2),S(k2+3) from kS0/kS1; P writes
  // pW0/pW1; PV(k2),PV(k2+1) from Plds[pR0]/[pR1] + vR0/vR1; K loads
  // (k2+4),(k2+5) -> kL0/kL1; V loads (k2+4),(k2+5) -> vR0/vR1 (after PV).
  auto pair = [&](bf16x8 (&kS0)[2], bf16x8 (&kS1)[2],
                  bf16x8 (&kL0)[2], bf16x8 (&kL1)[2],
                  bf16x8 (&vR0)[4], bf16x8 (&vR1)[4],
                  int k2, int pW0, int pW1, int pR0, int pR1) {
    const int jA = (k2 + 4) & 63, jB = (k2 + 5) & 63;

    // K prefetch (consumed by S one pair out)
#pragma unroll
    for (int ks = 0; ks < 2; ++ks)
      kL0[ks] = *reinterpret_cast<const bf16x8*>(
          Kbase + (size_t)(4 * jA + ks) * 512);
#pragma unroll
    for (int ks = 0; ks < 2; ++ks)
      kL1[ks] = *reinterpret_cast<const bf16x8*>(
          Kbase + (size_t)(4 * jB + ks) * 512);

    // ---- S(k2+2) -> P[pW0]
    {
      f32x4 s = (f32x4){0.f, 0.f, 0.f, 0.f};
      s = MFMA32(aq[0], kS0[0], s);
      s = MFMA32(aq[1], kS0[1], s);
#pragma unroll
      for (int r = 0; r < 4; ++r) {
        float p = __expf(s[r]); lp[r] += p;
        Plds[pW0][qh * 16 + 4 * g + r][kq * 16 + c] = f2bf(p);
      }
    }
    // ---- S(k2+3) -> P[pW1]
    {
      f32x4 s = (f32x4){0.f, 0.f, 0.f, 0.f};
      s = MFMA32(aq[0], kS1[0], s);
      s = MFMA32(aq[1], kS1[1], s);
#pragma unroll
      for (int r = 0; r < 4; ++r) {
        float p = __expf(s[r]); lp[r] += p;
        Plds[pW1][qh * 16 + 4 * g + r][kq * 16 + c] = f2bf(p);
      }
    }

    // ---- PV(k2) from Plds[pR0] + vR0
    {
      bf16x8 pa0 = *reinterpret_cast<const bf16x8*>(&Plds[pR0][c][8 * g]);
      bf16x8 pa1 = *reinterpret_cast<const bf16x8*>(&Plds[pR0][16 + c][8 * g]);
      bf16x8 pa2 = *reinterpret_cast<const bf16x8*>(&Plds[pR0][32 + c][8 * g]);
      bf16x8 pa3 = *reinterpret_cast<const bf16x8*>(&Plds[pR0][48 + c][8 * g]);
      __builtin_amdgcn_s_setprio(1);
#pragma unroll
      for (int dt = 0; dt < 4; ++dt) {
        o[0][dt] = MFMA32(pa0, vR0[dt], o[0][dt]);
        o[1][dt] = MFMA32(pa1, vR0[dt], o[1][dt]);
        o[2][dt] = MFMA32(pa2, vR0[dt], o[2][dt]);
        o[3][dt] = MFMA32(pa3, vR0[dt], o[3][dt]);
      }
      __builtin_amdgcn_s_setprio(0);
    }
    // V(jA) into the just-consumed slot (in-wave WAR, compiler-ordered)
#pragma unroll
    for (int f = 0; f < 4; ++f)
      vR0[f] = *reinterpret_cast<const bf16x8*>(
          Vbase + (size_t)(f * 64 + jA) * 512);

    // ---- PV(k2+1) from Plds[pR1] + vR1
    {
      bf16x8 pa0 = *reinterpret_cast<const bf16x8*>(&Plds[pR1][c][8 * g]);
      bf16x8 pa1 = *reinterpret_cast<const bf16x8*>(&Plds[pR1][16 + c][8 * g]);
      bf16x8 pa2 = *reinterpret_cast<const bf16x8*>(&Plds[pR1][32 + c][8 * g]);
      bf16x8 pa3 = *reinterpret_cast<const bf16x8*>(&Plds[pR1][48 + c][8 * g]);
      __builtin_amdgcn_s_setprio(1);
#pragma unroll
      for (int dt = 0; dt < 4; ++dt) {
        o[0][dt] = MFMA32(pa0, vR1[dt], o[0][dt]);
        o[1][dt] = MFMA32(pa1, vR1[dt], o[1][dt]);
        o[2][dt] = MFMA32(pa2, vR1[dt], o[2][dt]);
        o[3][dt] = MFMA32(pa3, vR1[dt], o[3][dt]);
      }
      __builtin_amdgcn_s_setprio(0);
    }
#pragma unroll
    for (int f = 0; f < 4; ++f)
      vR1[f] = *reinterpret_cast<const bf16x8*>(
          Vbase + (size_t)(f * 64 + jB) * 512);

    BARRIER_LGKM();
  };

  // pairs: 2k = 0..58 in the loop, final even pair 2k = 60 after.
#pragma unroll 1
  for (int k2 = 0; k2 < 60; k2 += 4) {
    pair(kbuf[2], kbuf[3], kbuf[0], kbuf[1], vbuf[0], vbuf[1], k2,     2, 3, 0, 1);
    pair(kbuf[0], kbuf[1], kbuf[2], kbuf[3], vbuf[2], vbuf[3], k2 + 2, 0, 1, 2, 3);
  }
  pair(kbuf[2], kbuf[3], kbuf[0], kbuf[1], vbuf[0], vbuf[1], 60, 2, 3, 0, 1);

  // ---- epilogue: PV(62) from Plds[2]+vbuf[2], PV(63) from Plds[3]+vbuf[3]
#pragma unroll
  for (int e = 0; e < 2; ++e) {
    const int pb = 2 + e;
    bf16x8 pa0 = *reinterpret_cast<const bf16x8*>(&Plds[pb][c][8 * g]);
    bf16x8 pa1 = *reinterpret_cast<const bf16x8*>(&Plds[pb][16 + c][8 * g]);
    bf16x8 pa2 = *reinterpret_cast<const bf16x8*>(&Plds[pb][32 + c][8 * g]);
    bf16x8 pa3 = *reinterpret_cast<const bf16x8*>(&Plds[pb][48 + c][8 * g]);
#pragma unroll
    for (int dt = 0; dt < 4; ++dt) {
      o[0][dt] = MFMA32(pa0, vbuf[pb][dt], o[0][dt]);
      o[1][dt] = MFMA32(pa1, vbuf[pb][dt], o[1][dt]);
      o[2][dt] = MFMA32(pa2, vbuf[pb][dt], o[2][dt]);
      o[3][dt] = MFMA32(pa3, vbuf[pb][dt], o[3][dt]);
    }
  }

  // ---- denominator: reduce lp over 16 c-lanes, combine the 2 kq halves
#pragma unroll
  for (int r = 0; r < 4; ++r) {
    float v = lp[r];
    v += __shfl_xor(v, 1); v += __shfl_xor(v, 2);
    v += __shfl_xor(v, 4); v += __shfl_xor(v, 8);
    lp[r] = v;
  }
  if (c == 0) {
#pragma unroll
    for (int r = 0; r < 4; ++r) Lp[kq][qh * 16 + 4 * g + r] = lp[r];
  }
  __syncthreads();

  float* outb = out + ((size_t)b * N_ + q0) * D_;
#pragma unroll
  for (int qf2 = 0; qf2 < 4; ++qf2)
#pragma unroll
    for (int r = 0; r < 4; ++r) {
      int ql = qf2 * 16 + 4 * g + r;
      float L = Lp[0][ql] + Lp[1][ql];
      float inv = 1.0f / L;
#pragma unroll
      for (int df = 0; df < 4; ++df)
        outb[(size_t)ql * D_ + w * 64 + df * 16 + c] = o[qf2][df][r] * inv;
    }
}

// ---------------------------------------------------------------------------
extern "C" void kernel_launch(void* const* d_in, const int* in_sizes, int n_in,
                              void* d_out, int out_size, void* d_ws, size_t ws_size,
                              hipStream_t stream) {
  const float* X  = (const float*)d_in[0];
  const float* h  = (const float*)d_in[1];
  const float* WQ = (const float*)d_in[2];
  const float* bQ = (const float*)d_in[3];
  const float* WK = (const float*)d_in[4];
  const float* bK = (const float*)d_in[5];
  float* out = (float*)d_out;

  u16* Vf = (u16*)d_ws;                                // 16 MB
  u16* Qf = Vf + (size_t)B_ * D_ * N_;                 // 2 MB
  u16* Kf = Qf + (size_t)B_ * N_ * DK_;                // 2 MB

  prep_kernel<<<dim3(256), dim3(256), 0, stream>>>(h, X, WQ, bQ, WK, bK, Qf, Kf, Vf);
  attn_kernel<<<dim3(256), dim3(512), 0, stream>>>(Qf, Kf, Vf, out);
}